// Round 5
// baseline (150.482 us; speedup 1.0000x reference)
//
#include <hip/hip_runtime.h>
#include <hip/hip_bf16.h>

#define FP const float* __restrict__

// ---------- helpers ----------
// load 8 contiguous floats (32B aligned)
__device__ __forceinline__ void load8(const float* p, float* o) {
    const float4* v = reinterpret_cast<const float4*>(p);
    float4 a = v[0], b = v[1];
    o[0] = a.x; o[1] = a.y; o[2] = a.z; o[3] = a.w;
    o[4] = b.x; o[5] = b.y; o[6] = b.z; o[7] = b.w;
}

__device__ __forceinline__ float sigmoidf_(float x) {
    return 1.0f / (1.0f + __expf(-x));
}

// store 16 floats as four float4 (64B)
__device__ __forceinline__ void store16_f32(float* p, const float* y) {
    float4* d = reinterpret_cast<float4*>(p);
    d[0] = make_float4(y[0], y[1], y[2], y[3]);
    d[1] = make_float4(y[4], y[5], y[6], y[7]);
    d[2] = make_float4(y[8], y[9], y[10], y[11]);
    d[3] = make_float4(y[12], y[13], y[14], y[15]);
}

// ---------- K1: out0 [B,16] and out1 [B,N,16] ----------
__global__ __launch_bounds__(256) void k_small(FP x0, FP x1, FP x2, FP W0, FP b0, FP W1, FP b1,
                                               float* __restrict__ out0,
                                               float* __restrict__ out1) {
    int b = blockIdx.x, tid = threadIdx.x;
    __shared__ float s2max[256], s2min[256], sx1[256], sx0[8], m1max[8], m1min[8];
    int i = tid >> 3, c = tid & 7;
    {
        // _reduce(x2): max_j (j==i?0:x2[b,i,j,c]), min_j (j==i?1:...)
        const float* p = x2 + ((size_t)(b * 32 + i) * 32) * 8 + c;
        float vmax = -1e30f, vmin = 1e30f;
        for (int j2 = 0; j2 < 32; ++j2) {
            float v = p[j2 * 8];
            vmax = fmaxf(vmax, (j2 == i) ? 0.0f : v);
            vmin = fminf(vmin, (j2 == i) ? 1.0f : v);
        }
        s2max[tid] = vmax;
        s2min[tid] = vmin;
    }
    sx1[tid] = x1[(size_t)b * 256 + tid];
    if (tid < 8) sx0[tid] = x0[b * 8 + tid];
    __syncthreads();
    if (tid < 8) {
        // _reduce(x1): plain max/min over N (ndim==3 -> no self-exclusion)
        float mx = -1e30f, mn = 1e30f;
        for (int ii = 0; ii < 32; ++ii) {
            float v = sx1[ii * 8 + tid];
            mx = fmaxf(mx, v);
            mn = fminf(mn, v);
        }
        m1max[tid] = mx;
        m1min[tid] = mn;
    }
    __syncthreads();
    // out1: f1 = [x0 | x1 | r2max | r2min] @ W1 ; 512 outputs, 2 per thread
#pragma unroll
    for (int q = 0; q < 2; ++q) {
        int idx = tid + q * 256;
        int i2 = idx >> 4, o = idx & 15;
        float acc = b1[o];
#pragma unroll
        for (int cc = 0; cc < 8; ++cc) {
            acc += sx0[cc] * W1[cc * 16 + o];
            acc += sx1[i2 * 8 + cc] * W1[(8 + cc) * 16 + o];
            acc += s2max[i2 * 8 + cc] * W1[(16 + cc) * 16 + o];
            acc += s2min[i2 * 8 + cc] * W1[(24 + cc) * 16 + o];
        }
        out1[((size_t)b * 32 + i2) * 16 + o] = sigmoidf_(acc);
    }
    // out0: f0 = [x0 | max_n x1 | min_n x1] @ W0
    if (tid < 16) {
        int o = tid;
        float acc = b0[o];
#pragma unroll
        for (int cc = 0; cc < 8; ++cc) {
            acc += sx0[cc] * W0[cc * 16 + o];
            acc += m1max[cc] * W0[(8 + cc) * 16 + o];
            acc += m1min[cc] * W0[(16 + cc) * 16 + o];
        }
        out0[b * 16 + o] = sigmoidf_(acc);
    }
}

// ---------- K2: out2 [B,N,N,16], _reduce(x3) fused ----------
// h[b,i,j] = [x1[b,i] | x2[b,i,j] | r3max[b,i,j] | r3min[b,i,j]] (32)
// f2[b,i,j] = [h[b,i,j] | h[b,j,i]] (64)
__global__ __launch_bounds__(256) void k_out2(FP x1, FP x2, FP x3, FP W2, FP b2,
                                              float* __restrict__ out2) {
    __shared__ float Ws[64 * 16], bs[16];
    __shared__ float sx1[256], sx2ij[256], sx2ji[256];
    __shared__ float rAmax[256], rAmin[256], rBmax[256], rBmin[256];
    int bi = blockIdx.x;  // b*32 + i
    int b = bi >> 5, i = bi & 31;
    int tid = threadIdx.x, j = tid >> 3, c = tid & 7;
    for (int q = tid; q < 1024; q += 256) Ws[q] = W2[q];
    if (tid < 16) bs[tid] = b2[tid];
    sx1[tid] = x1[(size_t)b * 256 + tid];
    sx2ij[tid] = x2[(size_t)bi * 256 + tid];
    sx2ji[tid] = x2[(((size_t)b * 32 + j) * 32 + i) * 8 + c];
    {
        // A: r3[b,i,j,c] over w (diag w==j); B: r3[b,j,i,c] over w (diag w==i)
        const float* pA = x3 + ((size_t)bi * 32 + j) * 256 + c;
        const float* pB = x3 + (((size_t)b * 32 + j) * 32 + i) * 256 + c;
        float amax = -1e30f, amin = 1e30f, bmax = -1e30f, bmin = 1e30f;
        for (int w = 0; w < 32; ++w) {
            float va = pA[w * 8], vb = pB[w * 8];
            bool dA = (w == j), dB = (w == i);
            amax = fmaxf(amax, dA ? 0.0f : va);
            amin = fminf(amin, dA ? 1.0f : va);
            bmax = fmaxf(bmax, dB ? 0.0f : vb);
            bmin = fminf(bmin, dB ? 1.0f : vb);
        }
        rAmax[tid] = amax; rAmin[tid] = amin;
        rBmax[tid] = bmax; rBmin[tid] = bmin;
    }
    __syncthreads();
#pragma unroll
    for (int q = 0; q < 2; ++q) {
        int idx = tid + q * 256;
        int j2 = idx >> 4, o = idx & 15;
        float acc = bs[o];
#pragma unroll
        for (int cc = 0; cc < 8; ++cc) {
            int jc = j2 * 8 + cc;
            acc += sx1[i * 8 + cc] * Ws[(0 + cc) * 16 + o];
            acc += sx2ij[jc] * Ws[(8 + cc) * 16 + o];
            acc += rAmax[jc] * Ws[(16 + cc) * 16 + o];
            acc += rAmin[jc] * Ws[(24 + cc) * 16 + o];
            acc += sx1[jc] * Ws[(32 + cc) * 16 + o];
            acc += sx2ji[jc] * Ws[(40 + cc) * 16 + o];
            acc += rBmax[jc] * Ws[(48 + cc) * 16 + o];
            acc += rBmin[jc] * Ws[(56 + cc) * 16 + o];
        }
        out2[((size_t)bi * 32 + j2) * 16 + o] = sigmoidf_(acc);
    }
}

// ---------- K3: out3 [B,N,N,N,16] ----------
// f3[b,u,v,w] = concat over 6 perms of [x2[first2(perm)] | x3[perm(u,v,w)]]
// perm gather order: (u,v,w),(u,w,v),(v,u,w),(w,u,v),(v,w,u),(w,v,u)
__device__ __forceinline__ void fma_block(const float s[4][8], const float* Wrow,
                                          float acc[4][16]) {
#pragma unroll
    for (int c = 0; c < 8; ++c) {
        const float4* wv = reinterpret_cast<const float4*>(Wrow + c * 16);
#pragma unroll
        for (int o4 = 0; o4 < 4; ++o4) {
            float4 wq = wv[o4];
#pragma unroll
            for (int r = 0; r < 4; ++r) {
                acc[r][o4 * 4 + 0] += s[r][c] * wq.x;
                acc[r][o4 * 4 + 1] += s[r][c] * wq.y;
                acc[r][o4 * 4 + 2] += s[r][c] * wq.z;
                acc[r][o4 * 4 + 3] += s[r][c] * wq.w;
            }
        }
    }
}

__global__ __launch_bounds__(256) void k_out3(FP x2, FP x3, FP W3, FP b3,
                                              float* __restrict__ out3) {
    __shared__ float Ws[96 * 16];
    __shared__ float bs[16];
    for (int t = threadIdx.x; t < 1536; t += 256) Ws[t] = W3[t];
    if (threadIdx.x < 16) bs[threadIdx.x] = b3[threadIdx.x];
    __syncthreads();
    int t = blockIdx.x * 256 + threadIdx.x;  // 131072 threads, 4 w-rows each
    int w0 = (t & 7) * 4;
    int v = (t >> 3) & 31;
    int u = (t >> 8) & 31;
    int b = t >> 13;
    const size_t bu = (size_t)(b * 32 + u);
    const size_t bv = (size_t)(b * 32 + v);
    const size_t bb = (size_t)(b * 32);

    // w-independent x2 contributions: (u,v)->W rows 0..7, (v,u)->rows 32..39
    float x2uv[8], x2vu[8];
    load8(x2 + (bu * 32 + v) * 8, x2uv);
    load8(x2 + (bv * 32 + u) * 8, x2vu);
    float base[16];
#pragma unroll
    for (int o = 0; o < 16; ++o) base[o] = bs[o];
#pragma unroll
    for (int c = 0; c < 8; ++c) {
        const float4* wa = reinterpret_cast<const float4*>(Ws + (0 + c) * 16);
        const float4* wb = reinterpret_cast<const float4*>(Ws + (32 + c) * 16);
#pragma unroll
        for (int o4 = 0; o4 < 4; ++o4) {
            float4 qa = wa[o4], qb = wb[o4];
            base[o4 * 4 + 0] += x2uv[c] * qa.x + x2vu[c] * qb.x;
            base[o4 * 4 + 1] += x2uv[c] * qa.y + x2vu[c] * qb.y;
            base[o4 * 4 + 2] += x2uv[c] * qa.z + x2vu[c] * qb.z;
            base[o4 * 4 + 3] += x2uv[c] * qa.w + x2vu[c] * qb.w;
        }
    }
    float acc[4][16];
#pragma unroll
    for (int r = 0; r < 4; ++r)
#pragma unroll
        for (int o = 0; o < 16; ++o) acc[r][o] = base[o];

    float s[4][8];
    // x2 (u,w) -> rows 16..23
#pragma unroll
    for (int r = 0; r < 4; ++r) load8(x2 + (bu * 32 + (w0 + r)) * 8, s[r]);
    fma_block(s, Ws + 16 * 16, acc);
    // x2 (w,u) -> rows 48..55
#pragma unroll
    for (int r = 0; r < 4; ++r) load8(x2 + ((bb + (w0 + r)) * 32 + u) * 8, s[r]);
    fma_block(s, Ws + 48 * 16, acc);
    // x2 (v,w) -> rows 64..71
#pragma unroll
    for (int r = 0; r < 4; ++r) load8(x2 + (bv * 32 + (w0 + r)) * 8, s[r]);
    fma_block(s, Ws + 64 * 16, acc);
    // x2 (w,v) -> rows 80..87
#pragma unroll
    for (int r = 0; r < 4; ++r) load8(x2 + ((bb + (w0 + r)) * 32 + v) * 8, s[r]);
    fma_block(s, Ws + 80 * 16, acc);
    // x3 (u,v,w) -> rows 8..15
#pragma unroll
    for (int r = 0; r < 4; ++r) load8(x3 + ((bu * 32 + v) * 32 + (w0 + r)) * 8, s[r]);
    fma_block(s, Ws + 8 * 16, acc);
    // x3 (u,w,v) -> rows 24..31
#pragma unroll
    for (int r = 0; r < 4; ++r) load8(x3 + ((bu * 32 + (w0 + r)) * 32 + v) * 8, s[r]);
    fma_block(s, Ws + 24 * 16, acc);
    // x3 (v,u,w) -> rows 40..47
#pragma unroll
    for (int r = 0; r < 4; ++r) load8(x3 + ((bv * 32 + u) * 32 + (w0 + r)) * 8, s[r]);
    fma_block(s, Ws + 40 * 16, acc);
    // x3 (w,u,v) -> rows 56..63
#pragma unroll
    for (int r = 0; r < 4; ++r) load8(x3 + (((bb + (w0 + r)) * 32 + u) * 32 + v) * 8, s[r]);
    fma_block(s, Ws + 56 * 16, acc);
    // x3 (v,w,u) -> rows 72..79
#pragma unroll
    for (int r = 0; r < 4; ++r) load8(x3 + ((bv * 32 + (w0 + r)) * 32 + u) * 8, s[r]);
    fma_block(s, Ws + 72 * 16, acc);
    // x3 (w,v,u) -> rows 88..95
#pragma unroll
    for (int r = 0; r < 4; ++r) load8(x3 + (((bb + (w0 + r)) * 32 + v) * 32 + u) * 8, s[r]);
    fma_block(s, Ws + 88 * 16, acc);

    size_t row0 = ((bu * 32 + v) * 32 + w0);
#pragma unroll
    for (int r = 0; r < 4; ++r) {
        float y[16];
#pragma unroll
        for (int o = 0; o < 16; ++o) y[o] = sigmoidf_(acc[r][o]);
        store16_f32(out3 + (row0 + r) * 16, y);
    }
}

extern "C" void kernel_launch(void* const* d_in, const int* in_sizes, int n_in, void* d_out,
                              int out_size, void* d_ws, size_t ws_size, hipStream_t stream) {
    // Identify inputs by their UNIQUE flat element counts (robust to ordering).
    //   x0=128, x1=4096, x2=131072, x3=4194304, W0=384, W1=512, W2=1024,
    //   W3=1536, b0..b3=16 (all-zero per setup_inputs)
    const float *x0 = nullptr, *x1 = nullptr, *x2 = nullptr, *x3 = nullptr;
    const float *W0 = nullptr, *W1 = nullptr, *W2 = nullptr, *W3 = nullptr;
    const float* bb[4] = {nullptr, nullptr, nullptr, nullptr};
    int nb = 0;
    for (int k = 0; k < n_in; ++k) {
        const float* p = (const float*)d_in[k];
        switch (in_sizes[k]) {
            case 128:     x0 = p; break;
            case 4096:    x1 = p; break;
            case 131072:  x2 = p; break;
            case 4194304: x3 = p; break;
            case 384:     W0 = p; break;
            case 512:     W1 = p; break;
            case 1024:    W2 = p; break;
            case 1536:    W3 = p; break;
            case 16:      if (nb < 4) bb[nb++] = p; break;
            default: break;
        }
    }
    if (!x0) x0 = (const float*)d_in[0];
    if (!x1) x1 = (const float*)d_in[1];
    if (!x2) x2 = (const float*)d_in[2];
    if (!x3) x3 = (const float*)d_in[3];
    if (!W0) W0 = (const float*)d_in[4];
    if (!W1) W1 = (const float*)d_in[6];
    if (!W2) W2 = (const float*)d_in[8];
    if (!W3) W3 = (const float*)d_in[10];
    const float* b0 = nb > 0 ? bb[0] : (const float*)d_in[5];
    const float* b1 = nb > 1 ? bb[1] : (const float*)d_in[7];
    const float* b2 = nb > 2 ? bb[2] : (const float*)d_in[9];
    const float* b3 = nb > 3 ? bb[3] : (const float*)d_in[11];

    // Output is FP32 (reference returns float32; harness reads per reference
    // output dtype — the "(bf16" in the test label is literal f-string text).
    float* out = (float*)d_out;
    float* out0 = out;           // [16,16]          = 256
    float* out1 = out + 256;     // [16,32,16]       = 8192
    float* out2 = out + 8448;    // [16,32,32,16]    = 262144
    float* out3 = out + 270592;  // [16,32,32,32,16] = 8388608

    k_small<<<16, 256, 0, stream>>>(x0, x1, x2, W0, b0, W1, b1, out0, out1);
    k_out2<<<512, 256, 0, stream>>>(x1, x2, x3, W2, b2, out2);
    k_out3<<<512, 256, 0, stream>>>(x2, x3, W3, b3, out3);
}

// Round 6
// 124.201 us; speedup vs baseline: 1.2116x; 1.2116x over previous
//
#include <hip/hip_runtime.h>
#include <hip/hip_bf16.h>

#define FP const float* __restrict__

// ---------- helpers ----------
__device__ __forceinline__ void load8(const float* p, float* o) {
    const float4* v = reinterpret_cast<const float4*>(p);
    float4 a = v[0], b = v[1];
    o[0] = a.x; o[1] = a.y; o[2] = a.z; o[3] = a.w;
    o[4] = b.x; o[5] = b.y; o[6] = b.z; o[7] = b.w;
}

__device__ __forceinline__ float sigmoidf_(float x) {
    return 1.0f / (1.0f + __expf(-x));
}

__device__ __forceinline__ void store16_f32(float* p, const float* y) {
    float4* d = reinterpret_cast<float4*>(p);
    d[0] = make_float4(y[0], y[1], y[2], y[3]);
    d[1] = make_float4(y[4], y[5], y[6], y[7]);
    d[2] = make_float4(y[8], y[9], y[10], y[11]);
    d[3] = make_float4(y[12], y[13], y[14], y[15]);
}

// 2-row FMA block: acc[r][o] += s[r][c] * Wrow[c*16+o]
__device__ __forceinline__ void fma_block2(const float s[2][8], const float* Wrow,
                                           float acc[2][16]) {
#pragma unroll
    for (int c = 0; c < 8; ++c) {
        const float4* wv = reinterpret_cast<const float4*>(Wrow + c * 16);
#pragma unroll
        for (int o4 = 0; o4 < 4; ++o4) {
            float4 wq = wv[o4];
#pragma unroll
            for (int r = 0; r < 2; ++r) {
                acc[r][o4 * 4 + 0] += s[r][c] * wq.x;
                acc[r][o4 * 4 + 1] += s[r][c] * wq.y;
                acc[r][o4 * 4 + 2] += s[r][c] * wq.z;
                acc[r][o4 * 4 + 3] += s[r][c] * wq.w;
            }
        }
    }
}

// Fused kernel. Block regions:
//   [0,1024)    : out3 (2 w-rows/thread), XCD-swizzled so block%8 == b%8
//   [1024,1536) : out2 (+fused _reduce(x3)), XCD-swizzled likewise
//   [1536,1552) : out0+out1 (one block per batch)
__global__ __launch_bounds__(256) void k_fused(
    FP x0, FP x1, FP x2, FP x3, FP W0, FP b0, FP W1, FP b1, FP W2, FP b2, FP W3, FP b3,
    float* __restrict__ out0, float* __restrict__ out1, float* __restrict__ out2,
    float* __restrict__ out3) {
    __shared__ float sm[3072];  // 12 KB, aliased per branch
    const int blk = blockIdx.x;
    const int tid = threadIdx.x;

    if (blk < 1024) {
        // ================= out3 =================
        float* Ws = sm;         // 1536
        float* bs = sm + 1536;  // 16
        for (int t = tid; t < 1536; t += 256) Ws[t] = W3[t];
        if (tid < 16) bs[tid] = b3[tid];
        __syncthreads();
        // XCD swizzle: physical blk -> logical (batch lb, slice r64)
        int xcd = blk & 7, inner = blk >> 3;
        int r64 = inner & 63, hb = inner >> 6;
        int lb = xcd | (hb << 3);                  // batch 0..15
        int t3 = (lb * 64 + r64) * 256 + tid;      // global out3 thread id
        int w0 = (t3 & 15) * 2;
        int v = (t3 >> 4) & 31;
        int u = (t3 >> 9) & 31;
        int b = t3 >> 14;  // == lb
        const size_t bu = (size_t)(b * 32 + u);
        const size_t bv = (size_t)(b * 32 + v);
        const size_t bb = (size_t)(b * 32);

        // w-independent x2 terms: (u,v)->W rows 0..7, (v,u)->rows 32..39
        float x2uv[8], x2vu[8];
        load8(x2 + (bu * 32 + v) * 8, x2uv);
        load8(x2 + (bv * 32 + u) * 8, x2vu);
        float acc[2][16];
        {
            float base[16];
#pragma unroll
            for (int o = 0; o < 16; ++o) base[o] = bs[o];
#pragma unroll
            for (int c = 0; c < 8; ++c) {
                const float4* wa = reinterpret_cast<const float4*>(Ws + (0 + c) * 16);
                const float4* wb = reinterpret_cast<const float4*>(Ws + (32 + c) * 16);
#pragma unroll
                for (int o4 = 0; o4 < 4; ++o4) {
                    float4 qa = wa[o4], qb = wb[o4];
                    base[o4 * 4 + 0] += x2uv[c] * qa.x + x2vu[c] * qb.x;
                    base[o4 * 4 + 1] += x2uv[c] * qa.y + x2vu[c] * qb.y;
                    base[o4 * 4 + 2] += x2uv[c] * qa.z + x2vu[c] * qb.z;
                    base[o4 * 4 + 3] += x2uv[c] * qa.w + x2vu[c] * qb.w;
                }
            }
#pragma unroll
            for (int r = 0; r < 2; ++r)
#pragma unroll
                for (int o = 0; o < 16; ++o) acc[r][o] = base[o];
        }

        float s[2][8];
        // x2 (u,w) -> rows 16..23
#pragma unroll
        for (int r = 0; r < 2; ++r) load8(x2 + (bu * 32 + (w0 + r)) * 8, s[r]);
        fma_block2(s, Ws + 16 * 16, acc);
        // x2 (w,u) -> rows 48..55
#pragma unroll
        for (int r = 0; r < 2; ++r) load8(x2 + ((bb + (w0 + r)) * 32 + u) * 8, s[r]);
        fma_block2(s, Ws + 48 * 16, acc);
        // x2 (v,w) -> rows 64..71
#pragma unroll
        for (int r = 0; r < 2; ++r) load8(x2 + (bv * 32 + (w0 + r)) * 8, s[r]);
        fma_block2(s, Ws + 64 * 16, acc);
        // x2 (w,v) -> rows 80..87
#pragma unroll
        for (int r = 0; r < 2; ++r) load8(x2 + ((bb + (w0 + r)) * 32 + v) * 8, s[r]);
        fma_block2(s, Ws + 80 * 16, acc);
        // x3 (u,v,w) -> rows 8..15
#pragma unroll
        for (int r = 0; r < 2; ++r) load8(x3 + ((bu * 32 + v) * 32 + (w0 + r)) * 8, s[r]);
        fma_block2(s, Ws + 8 * 16, acc);
        // x3 (u,w,v) -> rows 24..31
#pragma unroll
        for (int r = 0; r < 2; ++r) load8(x3 + ((bu * 32 + (w0 + r)) * 32 + v) * 8, s[r]);
        fma_block2(s, Ws + 24 * 16, acc);
        // x3 (v,u,w) -> rows 40..47
#pragma unroll
        for (int r = 0; r < 2; ++r) load8(x3 + ((bv * 32 + u) * 32 + (w0 + r)) * 8, s[r]);
        fma_block2(s, Ws + 40 * 16, acc);
        // x3 (w,u,v) -> rows 56..63
#pragma unroll
        for (int r = 0; r < 2; ++r) load8(x3 + (((bb + (w0 + r)) * 32 + u) * 32 + v) * 8, s[r]);
        fma_block2(s, Ws + 56 * 16, acc);
        // x3 (v,w,u) -> rows 72..79
#pragma unroll
        for (int r = 0; r < 2; ++r) load8(x3 + ((bv * 32 + (w0 + r)) * 32 + u) * 8, s[r]);
        fma_block2(s, Ws + 72 * 16, acc);
        // x3 (w,v,u) -> rows 88..95
#pragma unroll
        for (int r = 0; r < 2; ++r) load8(x3 + (((bb + (w0 + r)) * 32 + v) * 32 + u) * 8, s[r]);
        fma_block2(s, Ws + 88 * 16, acc);

        size_t row0 = ((bu * 32 + v) * 32 + w0);
#pragma unroll
        for (int r = 0; r < 2; ++r) {
            float y[16];
#pragma unroll
            for (int o = 0; o < 16; ++o) y[o] = sigmoidf_(acc[r][o]);
            store16_f32(out3 + (row0 + r) * 16, y);
        }
    } else if (blk < 1536) {
        // ================= out2 (+reduce x3) =================
        float* Ws = sm;            // 1024
        float* bs = sm + 1024;     // 16
        float* sx1 = sm + 1040;    // 256
        float* sx2ij = sm + 1296;  // 256
        float* sx2ji = sm + 1552;  // 256
        float* rAmax = sm + 1808;  // 256
        float* rAmin = sm + 2064;  // 256
        float* rBmax = sm + 2320;  // 256
        float* rBmin = sm + 2576;  // 256
        int q = blk - 1024;
        int xcd = q & 7, inner = q >> 3;
        int i = inner & 31;
        int b = xcd | ((inner >> 5) << 3);
        int bi = b * 32 + i;
        int j = tid >> 3, c = tid & 7;
        for (int t = tid; t < 1024; t += 256) Ws[t] = W2[t];
        if (tid < 16) bs[tid] = b2[tid];
        sx1[tid] = x1[(size_t)b * 256 + tid];
        sx2ij[tid] = x2[(size_t)bi * 256 + tid];
        sx2ji[tid] = x2[(((size_t)b * 32 + j) * 32 + i) * 8 + c];
        {
            // A: r3[b,i,j,c] over w (diag w==j); B: r3[b,j,i,c] over w (diag w==i)
            const float* pA = x3 + ((size_t)bi * 32 + j) * 256 + c;
            const float* pB = x3 + (((size_t)b * 32 + j) * 32 + i) * 256 + c;
            float amax = -1e30f, amin = 1e30f, bmax = -1e30f, bmin = 1e30f;
            for (int w = 0; w < 32; ++w) {
                float va = pA[w * 8], vb = pB[w * 8];
                bool dA = (w == j), dB = (w == i);
                amax = fmaxf(amax, dA ? 0.0f : va);
                amin = fminf(amin, dA ? 1.0f : va);
                bmax = fmaxf(bmax, dB ? 0.0f : vb);
                bmin = fminf(bmin, dB ? 1.0f : vb);
            }
            rAmax[tid] = amax; rAmin[tid] = amin;
            rBmax[tid] = bmax; rBmin[tid] = bmin;
        }
        __syncthreads();
#pragma unroll
        for (int qq = 0; qq < 2; ++qq) {
            int idx = tid + qq * 256;
            int j2 = idx >> 4, o = idx & 15;
            float acc = bs[o];
#pragma unroll
            for (int cc = 0; cc < 8; ++cc) {
                int jc = j2 * 8 + cc;
                acc += sx1[i * 8 + cc] * Ws[(0 + cc) * 16 + o];
                acc += sx2ij[jc] * Ws[(8 + cc) * 16 + o];
                acc += rAmax[jc] * Ws[(16 + cc) * 16 + o];
                acc += rAmin[jc] * Ws[(24 + cc) * 16 + o];
                acc += sx1[jc] * Ws[(32 + cc) * 16 + o];
                acc += sx2ji[jc] * Ws[(40 + cc) * 16 + o];
                acc += rBmax[jc] * Ws[(48 + cc) * 16 + o];
                acc += rBmin[jc] * Ws[(56 + cc) * 16 + o];
            }
            out2[((size_t)bi * 32 + j2) * 16 + o] = sigmoidf_(acc);
        }
    } else {
        // ================= out0 + out1 =================
        float* s2max = sm;          // 256
        float* s2min = sm + 256;    // 256
        float* sx1 = sm + 512;      // 256
        float* sx0 = sm + 768;      // 8
        float* m1max = sm + 776;    // 8
        float* m1min = sm + 784;    // 8
        int b = blk - 1536;
        int i = tid >> 3, c = tid & 7;
        {
            const float* p = x2 + ((size_t)(b * 32 + i) * 32) * 8 + c;
            float vmax = -1e30f, vmin = 1e30f;
            for (int j2 = 0; j2 < 32; ++j2) {
                float v = p[j2 * 8];
                vmax = fmaxf(vmax, (j2 == i) ? 0.0f : v);
                vmin = fminf(vmin, (j2 == i) ? 1.0f : v);
            }
            s2max[tid] = vmax;
            s2min[tid] = vmin;
        }
        sx1[tid] = x1[(size_t)b * 256 + tid];
        if (tid < 8) sx0[tid] = x0[b * 8 + tid];
        __syncthreads();
        if (tid < 8) {
            float mx = -1e30f, mn = 1e30f;
            for (int ii = 0; ii < 32; ++ii) {
                float v = sx1[ii * 8 + tid];
                mx = fmaxf(mx, v);
                mn = fminf(mn, v);
            }
            m1max[tid] = mx;
            m1min[tid] = mn;
        }
        __syncthreads();
#pragma unroll
        for (int qq = 0; qq < 2; ++qq) {
            int idx = tid + qq * 256;
            int i2 = idx >> 4, o = idx & 15;
            float acc = b1[o];
#pragma unroll
            for (int cc = 0; cc < 8; ++cc) {
                acc += sx0[cc] * W1[cc * 16 + o];
                acc += sx1[i2 * 8 + cc] * W1[(8 + cc) * 16 + o];
                acc += s2max[i2 * 8 + cc] * W1[(16 + cc) * 16 + o];
                acc += s2min[i2 * 8 + cc] * W1[(24 + cc) * 16 + o];
            }
            out1[((size_t)b * 32 + i2) * 16 + o] = sigmoidf_(acc);
        }
        if (tid < 16) {
            int o = tid;
            float acc = b0[o];
#pragma unroll
            for (int cc = 0; cc < 8; ++cc) {
                acc += sx0[cc] * W0[cc * 16 + o];
                acc += m1max[cc] * W0[(8 + cc) * 16 + o];
                acc += m1min[cc] * W0[(16 + cc) * 16 + o];
            }
            out0[b * 16 + o] = sigmoidf_(acc);
        }
    }
}

extern "C" void kernel_launch(void* const* d_in, const int* in_sizes, int n_in, void* d_out,
                              int out_size, void* d_ws, size_t ws_size, hipStream_t stream) {
    // Identify inputs by their UNIQUE flat element counts (robust to ordering).
    const float *x0 = nullptr, *x1 = nullptr, *x2 = nullptr, *x3 = nullptr;
    const float *W0 = nullptr, *W1 = nullptr, *W2 = nullptr, *W3 = nullptr;
    const float* bb[4] = {nullptr, nullptr, nullptr, nullptr};
    int nb = 0;
    for (int k = 0; k < n_in; ++k) {
        const float* p = (const float*)d_in[k];
        switch (in_sizes[k]) {
            case 128:     x0 = p; break;
            case 4096:    x1 = p; break;
            case 131072:  x2 = p; break;
            case 4194304: x3 = p; break;
            case 384:     W0 = p; break;
            case 512:     W1 = p; break;
            case 1024:    W2 = p; break;
            case 1536:    W3 = p; break;
            case 16:      if (nb < 4) bb[nb++] = p; break;
            default: break;
        }
    }
    if (!x0) x0 = (const float*)d_in[0];
    if (!x1) x1 = (const float*)d_in[1];
    if (!x2) x2 = (const float*)d_in[2];
    if (!x3) x3 = (const float*)d_in[3];
    if (!W0) W0 = (const float*)d_in[4];
    if (!W1) W1 = (const float*)d_in[6];
    if (!W2) W2 = (const float*)d_in[8];
    if (!W3) W3 = (const float*)d_in[10];
    const float* b0 = nb > 0 ? bb[0] : (const float*)d_in[5];
    const float* b1 = nb > 1 ? bb[1] : (const float*)d_in[7];
    const float* b2 = nb > 2 ? bb[2] : (const float*)d_in[9];
    const float* b3 = nb > 3 ? bb[3] : (const float*)d_in[11];

    // Output is FP32 (reference output dtype), concatenated flat in return order.
    float* out = (float*)d_out;
    float* out0 = out;           // [16,16]          = 256
    float* out1 = out + 256;     // [16,32,16]       = 8192
    float* out2 = out + 8448;    // [16,32,32,16]    = 262144
    float* out3 = out + 270592;  // [16,32,32,32,16] = 8388608

    k_fused<<<1552, 256, 0, stream>>>(x0, x1, x2, x3, W0, b0, W1, b1, W2, b2, W3, b3,
                                      out0, out1, out2, out3);
}

// Round 7
// 120.428 us; speedup vs baseline: 1.2496x; 1.0313x over previous
//
#include <hip/hip_runtime.h>
#include <hip/hip_bf16.h>

#define FP const float* __restrict__

typedef __attribute__((ext_vector_type(8))) short bf16x8;
typedef __attribute__((ext_vector_type(4))) float f32x4;

// ---------- helpers ----------
__device__ __forceinline__ void load8(const float* p, float* o) {
    const float4* v = reinterpret_cast<const float4*>(p);
    float4 a = v[0], b = v[1];
    o[0] = a.x; o[1] = a.y; o[2] = a.z; o[3] = a.w;
    o[4] = b.x; o[5] = b.y; o[6] = b.z; o[7] = b.w;
}

__device__ __forceinline__ float sigmoidf_(float x) {
    return 1.0f / (1.0f + __expf(-x));
}

__device__ __forceinline__ short f2bf(float x) {
    __hip_bfloat16 h = __float2bfloat16(x);
    return *reinterpret_cast<short*>(&h);
}

// load 8 contiguous floats -> bf16x8 fragment
__device__ __forceinline__ bf16x8 load8_bf(const float* p) {
    float v[8];
    load8(p, v);
    bf16x8 r;
#pragma unroll
    for (int j = 0; j < 8; ++j) r[j] = f2bf(v[j]);
    return r;
}

// Fused kernel. Block regions:
//   [0,8192)    : out3 via MFMA, 1 16-row tile per wave, XCD-swizzled (blk%8==b%8)
//   [8192,8704) : out2 (+fused _reduce(x3)), XCD-swizzled
//   [8704,8720) : out0+out1 (one block per batch)
__global__ __launch_bounds__(256) void k_fused(
    FP x0, FP x1, FP x2, FP x3, FP W0, FP b0, FP W1, FP b1, FP W2, FP b2, FP W3, FP b3,
    float* __restrict__ out0, float* __restrict__ out1, float* __restrict__ out2,
    float* __restrict__ out3) {
    __shared__ float sm[3072];  // used only by out2/small branches
    const int blk = blockIdx.x;
    const int tid = threadIdx.x;

    if (blk < 8192) {
        // ================= out3: MFMA 16x16x32 bf16, no LDS =================
        // GEMM: D[16 w-rows][16 outs] = F[16][96] @ W3[96][16] + b3
        // A-frag: lane holds F[m=lane&15][k=quad*8+j] == source (kb*4+quad), row w0+m
        // B-frag: lane holds W3[k=quad*8+j][n=lane&15], preloaded once
        // D: row = quad*4+reg, col = lane&15
        const int lane = tid & 63;
        const int wv = tid >> 6;       // wave in block (4 waves = 4 tiles)
        const int q = lane >> 4;       // quad 0..3
        const int mn = lane & 15;      // m for A, n for B/D
        // swizzle decode: tiles of batch b stay on XCD b%8
        const int xcd = blk & 7, inner = blk >> 3;
        const int b = xcd + 8 * (inner >> 9);
        const int tb = (inner & 511) * 4 + wv;  // 0..2047 within batch
        const int u = tb >> 6;
        const int v = (tb >> 1) & 31;
        const int w0 = (tb & 1) * 16;
        const int w = w0 + mn;  // A-source row for this lane
        const unsigned bu = b * 32 + u, bv = b * 32 + v, bbs = b * 32;

        // B fragments: W3 (96x16 row-major), k = kb*32 + q*8 + j, n = mn
        bf16x8 Bf[3];
#pragma unroll
        for (int kb = 0; kb < 3; ++kb) {
#pragma unroll
            for (int j = 0; j < 8; ++j)
                Bf[kb][j] = f2bf(W3[(kb * 32 + q * 8 + j) * 16 + mn]);
        }
        const float bias = b3[mn];
        f32x4 acc = {bias, bias, bias, bias};

        // perm gather order (verified passing R5/R6):
        //  s0 x2[u,v]  s1 x3[u,v,w] | s2 x2[u,w]  s3 x3[u,w,v]
        //  s4 x2[v,u]  s5 x3[v,u,w] | s6 x2[w,u]  s7 x3[w,u,v]
        //  s8 x2[v,w]  s9 x3[v,w,u] | s10 x2[w,v] s11 x3[w,v,u]
        {
            // kb0: q0=s0 q1=s1 q2=s2 q3=s3
            unsigned e2 = (q == 0) ? (bu * 32 + v) : (bu * 32 + w);
            unsigned e3 = (q == 1) ? ((bu * 32 + v) * 32 + w) : ((bu * 32 + w) * 32 + v);
            const float* p = (q & 1) ? (x3 + (size_t)e3 * 8) : (x2 + (size_t)e2 * 8);
            bf16x8 a = load8_bf(p);
            acc = __builtin_amdgcn_mfma_f32_16x16x32_bf16(a, Bf[0], acc, 0, 0, 0);
        }
        {
            // kb1: q0=s4 q1=s5 q2=s6 q3=s7
            unsigned e2 = (q == 0) ? (bv * 32 + u) : ((bbs + w) * 32 + u);
            unsigned e3 = (q == 1) ? ((bv * 32 + u) * 32 + w) : (((bbs + w) * 32 + u) * 32 + v);
            const float* p = (q & 1) ? (x3 + (size_t)e3 * 8) : (x2 + (size_t)e2 * 8);
            bf16x8 a = load8_bf(p);
            acc = __builtin_amdgcn_mfma_f32_16x16x32_bf16(a, Bf[1], acc, 0, 0, 0);
        }
        {
            // kb2: q0=s8 q1=s9 q2=s10 q3=s11
            unsigned e2 = (q == 0) ? (bv * 32 + w) : ((bbs + w) * 32 + v);
            unsigned e3 = (q == 1) ? ((bv * 32 + w) * 32 + u) : (((bbs + w) * 32 + v) * 32 + u);
            const float* p = (q & 1) ? (x3 + (size_t)e3 * 8) : (x2 + (size_t)e2 * 8);
            bf16x8 a = load8_bf(p);
            acc = __builtin_amdgcn_mfma_f32_16x16x32_bf16(a, Bf[2], acc, 0, 0, 0);
        }

        // epilogue: D row = q*4+rr, col = mn
        const size_t rowbase = ((size_t)bu * 32 + v) * 32 + w0;
#pragma unroll
        for (int rr = 0; rr < 4; ++rr) {
            out3[(rowbase + q * 4 + rr) * 16 + mn] = sigmoidf_(acc[rr]);
        }
    } else if (blk < 8704) {
        // ================= out2 (+reduce x3) =================
        float* Ws = sm;            // 1024
        float* bs = sm + 1024;     // 16
        float* sx1 = sm + 1040;    // 256
        float* sx2ij = sm + 1296;  // 256
        float* sx2ji = sm + 1552;  // 256
        float* rAmax = sm + 1808;  // 256
        float* rAmin = sm + 2064;  // 256
        float* rBmax = sm + 2320;  // 256
        float* rBmin = sm + 2576;  // 256
        int qq0 = blk - 8192;
        int xcd = qq0 & 7, inner = qq0 >> 3;
        int i = inner & 31;
        int b = xcd | ((inner >> 5) << 3);
        int bi = b * 32 + i;
        int j = tid >> 3, c = tid & 7;
        for (int t = tid; t < 1024; t += 256) Ws[t] = W2[t];
        if (tid < 16) bs[tid] = b2[tid];
        sx1[tid] = x1[(size_t)b * 256 + tid];
        sx2ij[tid] = x2[(size_t)bi * 256 + tid];
        sx2ji[tid] = x2[(((size_t)b * 32 + j) * 32 + i) * 8 + c];
        {
            // A: r3[b,i,j,c] over w (diag w==j); B: r3[b,j,i,c] over w (diag w==i)
            const float* pA = x3 + ((size_t)bi * 32 + j) * 256 + c;
            const float* pB = x3 + (((size_t)b * 32 + j) * 32 + i) * 256 + c;
            float amax = -1e30f, amin = 1e30f, bmax = -1e30f, bmin = 1e30f;
            for (int w = 0; w < 32; ++w) {
                float va = pA[w * 8], vb = pB[w * 8];
                bool dA = (w == j), dB = (w == i);
                amax = fmaxf(amax, dA ? 0.0f : va);
                amin = fminf(amin, dA ? 1.0f : va);
                bmax = fmaxf(bmax, dB ? 0.0f : vb);
                bmin = fminf(bmin, dB ? 1.0f : vb);
            }
            rAmax[tid] = amax; rAmin[tid] = amin;
            rBmax[tid] = bmax; rBmin[tid] = bmin;
        }
        __syncthreads();
#pragma unroll
        for (int qq = 0; qq < 2; ++qq) {
            int idx = tid + qq * 256;
            int j2 = idx >> 4, o = idx & 15;
            float acc = bs[o];
#pragma unroll
            for (int cc = 0; cc < 8; ++cc) {
                int jc = j2 * 8 + cc;
                acc += sx1[i * 8 + cc] * Ws[(0 + cc) * 16 + o];
                acc += sx2ij[jc] * Ws[(8 + cc) * 16 + o];
                acc += rAmax[jc] * Ws[(16 + cc) * 16 + o];
                acc += rAmin[jc] * Ws[(24 + cc) * 16 + o];
                acc += sx1[jc] * Ws[(32 + cc) * 16 + o];
                acc += sx2ji[jc] * Ws[(40 + cc) * 16 + o];
                acc += rBmax[jc] * Ws[(48 + cc) * 16 + o];
                acc += rBmin[jc] * Ws[(56 + cc) * 16 + o];
            }
            out2[((size_t)bi * 32 + j2) * 16 + o] = sigmoidf_(acc);
        }
    } else {
        // ================= out0 + out1 =================
        float* s2max = sm;        // 256
        float* s2min = sm + 256;  // 256
        float* sx1 = sm + 512;    // 256
        float* sx0 = sm + 768;    // 8
        float* m1max = sm + 776;  // 8
        float* m1min = sm + 784;  // 8
        int b = blk - 8704;
        int i = tid >> 3, c = tid & 7;
        {
            const float* p = x2 + ((size_t)(b * 32 + i) * 32) * 8 + c;
            float vmax = -1e30f, vmin = 1e30f;
            for (int j2 = 0; j2 < 32; ++j2) {
                float v = p[j2 * 8];
                vmax = fmaxf(vmax, (j2 == i) ? 0.0f : v);
                vmin = fminf(vmin, (j2 == i) ? 1.0f : v);
            }
            s2max[tid] = vmax;
            s2min[tid] = vmin;
        }
        sx1[tid] = x1[(size_t)b * 256 + tid];
        if (tid < 8) sx0[tid] = x0[b * 8 + tid];
        __syncthreads();
        if (tid < 8) {
            float mx = -1e30f, mn = 1e30f;
            for (int ii = 0; ii < 32; ++ii) {
                float v = sx1[ii * 8 + tid];
                mx = fmaxf(mx, v);
                mn = fminf(mn, v);
            }
            m1max[tid] = mx;
            m1min[tid] = mn;
        }
        __syncthreads();
#pragma unroll
        for (int qq = 0; qq < 2; ++qq) {
            int idx = tid + qq * 256;
            int i2 = idx >> 4, o = idx & 15;
            float acc = b1[o];
#pragma unroll
            for (int cc = 0; cc < 8; ++cc) {
                acc += sx0[cc] * W1[cc * 16 + o];
                acc += sx1[i2 * 8 + cc] * W1[(8 + cc) * 16 + o];
                acc += s2max[i2 * 8 + cc] * W1[(16 + cc) * 16 + o];
                acc += s2min[i2 * 8 + cc] * W1[(24 + cc) * 16 + o];
            }
            out1[((size_t)b * 32 + i2) * 16 + o] = sigmoidf_(acc);
        }
        if (tid < 16) {
            int o = tid;
            float acc = b0[o];
#pragma unroll
            for (int cc = 0; cc < 8; ++cc) {
                acc += sx0[cc] * W0[cc * 16 + o];
                acc += m1max[cc] * W0[(8 + cc) * 16 + o];
                acc += m1min[cc] * W0[(16 + cc) * 16 + o];
            }
            out0[b * 16 + o] = sigmoidf_(acc);
        }
    }
}

extern "C" void kernel_launch(void* const* d_in, const int* in_sizes, int n_in, void* d_out,
                              int out_size, void* d_ws, size_t ws_size, hipStream_t stream) {
    // Identify inputs by their UNIQUE flat element counts (robust to ordering).
    const float *x0 = nullptr, *x1 = nullptr, *x2 = nullptr, *x3 = nullptr;
    const float *W0 = nullptr, *W1 = nullptr, *W2 = nullptr, *W3 = nullptr;
    const float* bb[4] = {nullptr, nullptr, nullptr, nullptr};
    int nb = 0;
    for (int k = 0; k < n_in; ++k) {
        const float* p = (const float*)d_in[k];
        switch (in_sizes[k]) {
            case 128:     x0 = p; break;
            case 4096:    x1 = p; break;
            case 131072:  x2 = p; break;
            case 4194304: x3 = p; break;
            case 384:     W0 = p; break;
            case 512:     W1 = p; break;
            case 1024:    W2 = p; break;
            case 1536:    W3 = p; break;
            case 16:      if (nb < 4) bb[nb++] = p; break;
            default: break;
        }
    }
    if (!x0) x0 = (const float*)d_in[0];
    if (!x1) x1 = (const float*)d_in[1];
    if (!x2) x2 = (const float*)d_in[2];
    if (!x3) x3 = (const float*)d_in[3];
    if (!W0) W0 = (const float*)d_in[4];
    if (!W1) W1 = (const float*)d_in[6];
    if (!W2) W2 = (const float*)d_in[8];
    if (!W3) W3 = (const float*)d_in[10];
    const float* b0 = nb > 0 ? bb[0] : (const float*)d_in[5];
    const float* b1 = nb > 1 ? bb[1] : (const float*)d_in[7];
    const float* b2 = nb > 2 ? bb[2] : (const float*)d_in[9];
    const float* b3 = nb > 3 ? bb[3] : (const float*)d_in[11];

    // Output is FP32 (reference output dtype), concatenated flat in return order.
    float* out = (float*)d_out;
    float* out0 = out;           // [16,16]          = 256
    float* out1 = out + 256;     // [16,32,16]       = 8192
    float* out2 = out + 8448;    // [16,32,32,16]    = 262144
    float* out3 = out + 270592;  // [16,32,32,32,16] = 8388608

    k_fused<<<8720, 256, 0, stream>>>(x0, x1, x2, x3, W0, b0, W1, b1, W2, b2, W3, b3,
                                      out0, out1, out2, out3);
}

// Round 8
// 113.615 us; speedup vs baseline: 1.3245x; 1.0600x over previous
//
#include <hip/hip_runtime.h>
#include <hip/hip_bf16.h>

#define FP const float* __restrict__

typedef __attribute__((ext_vector_type(8))) short bf16x8;
typedef __attribute__((ext_vector_type(4))) float f32x4;

// ---------- helpers ----------
__device__ __forceinline__ void load8(const float* p, float* o) {
    const float4* v = reinterpret_cast<const float4*>(p);
    float4 a = v[0], b = v[1];
    o[0] = a.x; o[1] = a.y; o[2] = a.z; o[3] = a.w;
    o[4] = b.x; o[5] = b.y; o[6] = b.z; o[7] = b.w;
}

__device__ __forceinline__ float sigmoidf_(float x) {
    return 1.0f / (1.0f + __expf(-x));
}

__device__ __forceinline__ short f2bf(float x) {
    __hip_bfloat16 h = __float2bfloat16(x);
    return *reinterpret_cast<short*>(&h);
}

__device__ __forceinline__ bf16x8 load8_bf(const float* p) {
    float v[8];
    load8(p, v);
    bf16x8 r;
#pragma unroll
    for (int j = 0; j < 8; ++j) r[j] = f2bf(v[j]);
    return r;
}

// Fused kernel. Block regions:
//   [0,1024)    : out3 via MFMA, 8 16-row tiles per wave, XCD-swizzled (blk%8==b%8)
//   [1024,1536) : out2 (+fused _reduce(x3)), XCD-swizzled
//   [1536,1552) : out0+out1 (one block per batch)
__global__ __launch_bounds__(256) void k_fused(
    FP x0, FP x1, FP x2, FP x3, FP W0, FP b0, FP W1, FP b1, FP W2, FP b2, FP W3, FP b3,
    float* __restrict__ out0, float* __restrict__ out1, float* __restrict__ out2,
    float* __restrict__ out3) {
    __shared__ float sm[3072];
    const int blk = blockIdx.x;
    const int tid = threadIdx.x;

    if (blk < 1024) {
        // ================= out3: MFMA 16x16x32 bf16 =================
        // Per 16-row tile: D[16 w][16 o] = F[16][96] @ W3[96][16] + b3
        // A-frag: lane holds F[m=lane&15][k=quad*8+j] == one load8 from x2/x3
        // B-frag: lane holds W3[k=quad*8+j][n=lane&15], preloaded once per wave
        // D: row = quad*4+reg, col = lane&15
        const int lane = tid & 63;
        const int wv = tid >> 6;   // wave in block
        const int q = lane >> 4;   // quad 0..3
        const int mn = lane & 15;  // m for A, n for B/D
        // swizzle: batch b pinned to XCD b%8
        const int xcd = blk & 7, inner = blk >> 3;       // inner 0..127
        const int b = xcd + 8 * (inner >> 6);            // 16 batches
        const int base = (inner & 63) * 32 + wv * 8;     // tile-in-batch, 8 tiles/wave
        const int u = base >> 6;                         // constant across the 8 tiles
        const unsigned bu = b * 32 + u, bbs = b * 32;

        // B fragments + bias: once per wave, reused for 8 tiles (24 MFMAs)
        bf16x8 Bf[3];
#pragma unroll
        for (int kb = 0; kb < 3; ++kb) {
#pragma unroll
            for (int j = 0; j < 8; ++j)
                Bf[kb][j] = f2bf(W3[(kb * 32 + q * 8 + j) * 16 + mn]);
        }
        const float bias = b3[mn];
        float* lds = sm + wv * 256;  // per-wave 16x16 staging tile (no barriers needed)

#pragma unroll 2
        for (int tt = 0; tt < 8; ++tt) {
            const int tb = base + tt;
            const int v = (tb >> 1) & 31;
            const int w0 = (tb & 1) * 16;
            const int w = w0 + mn;  // A-source row for this lane
            const unsigned bv = bbs + v;
            f32x4 acc = {bias, bias, bias, bias};

            // perm gather order (verified passing R5-R7):
            //  s0 x2[u,v]  s1 x3[u,v,w] | s2 x2[u,w]  s3 x3[u,w,v]
            //  s4 x2[v,u]  s5 x3[v,u,w] | s6 x2[w,u]  s7 x3[w,u,v]
            //  s8 x2[v,w]  s9 x3[v,w,u] | s10 x2[w,v] s11 x3[w,v,u]
            {
                // kb0: q0=s0 q1=s1 q2=s2 q3=s3
                unsigned e2 = (q == 0) ? (bu * 32 + v) : (bu * 32 + w);
                unsigned e3 = (q == 1) ? ((bu * 32 + v) * 32 + w) : ((bu * 32 + w) * 32 + v);
                const float* p = (q & 1) ? (x3 + (size_t)e3 * 8) : (x2 + (size_t)e2 * 8);
                bf16x8 a = load8_bf(p);
                acc = __builtin_amdgcn_mfma_f32_16x16x32_bf16(a, Bf[0], acc, 0, 0, 0);
            }
            {
                // kb1: q0=s4 q1=s5 q2=s6 q3=s7
                unsigned e2 = (q == 0) ? (bv * 32 + u) : ((bbs + w) * 32 + u);
                unsigned e3 = (q == 1) ? ((bv * 32 + u) * 32 + w) : (((bbs + w) * 32 + u) * 32 + v);
                const float* p = (q & 1) ? (x3 + (size_t)e3 * 8) : (x2 + (size_t)e2 * 8);
                bf16x8 a = load8_bf(p);
                acc = __builtin_amdgcn_mfma_f32_16x16x32_bf16(a, Bf[1], acc, 0, 0, 0);
            }
            {
                // kb2: q0=s8 q1=s9 q2=s10 q3=s11
                unsigned e2 = (q == 0) ? (bv * 32 + w) : ((bbs + w) * 32 + v);
                unsigned e3 = (q == 1) ? ((bv * 32 + w) * 32 + u) : (((bbs + w) * 32 + v) * 32 + u);
                const float* p = (q & 1) ? (x3 + (size_t)e3 * 8) : (x2 + (size_t)e2 * 8);
                bf16x8 a = load8_bf(p);
                acc = __builtin_amdgcn_mfma_f32_16x16x32_bf16(a, Bf[2], acc, 0, 0, 0);
            }

            // epilogue: sigmoid -> per-wave LDS tile -> lane-contiguous float4 store
#pragma unroll
            for (int rr = 0; rr < 4; ++rr)
                lds[(q * 4 + rr) * 16 + mn] = sigmoidf_(acc[rr]);
            // wave-internal LDS ordering (compiler inserts lgkmcnt waits)
            float4 val = *reinterpret_cast<const float4*>(&lds[lane * 4]);
            const size_t rowbase = ((size_t)bu * 32 + v) * 32 + w0;
            *reinterpret_cast<float4*>(&out3[rowbase * 16 + lane * 4]) = val;
        }
    } else if (blk < 1536) {
        // ================= out2 (+reduce x3) =================
        float* Ws = sm;            // 1024
        float* bs = sm + 1024;     // 16
        float* sx1 = sm + 1040;    // 256
        float* sx2ij = sm + 1296;  // 256
        float* sx2ji = sm + 1552;  // 256
        float* rAmax = sm + 1808;  // 256
        float* rAmin = sm + 2064;  // 256
        float* rBmax = sm + 2320;  // 256
        float* rBmin = sm + 2576;  // 256
        int qq0 = blk - 1024;
        int xcd = qq0 & 7, inner = qq0 >> 3;
        int i = inner & 31;
        int b = xcd | ((inner >> 5) << 3);
        int bi = b * 32 + i;
        int j = tid >> 3, c = tid & 7;
        for (int t = tid; t < 1024; t += 256) Ws[t] = W2[t];
        if (tid < 16) bs[tid] = b2[tid];
        sx1[tid] = x1[(size_t)b * 256 + tid];
        sx2ij[tid] = x2[(size_t)bi * 256 + tid];
        sx2ji[tid] = x2[(((size_t)b * 32 + j) * 32 + i) * 8 + c];
        {
            // A: r3[b,i,j,c] over w (diag w==j); B: r3[b,j,i,c] over w (diag w==i)
            const float* pA = x3 + ((size_t)bi * 32 + j) * 256 + c;
            const float* pB = x3 + (((size_t)b * 32 + j) * 32 + i) * 256 + c;
            float amax = -1e30f, amin = 1e30f, bmax = -1e30f, bmin = 1e30f;
            for (int w = 0; w < 32; ++w) {
                float va = pA[w * 8], vb = pB[w * 8];
                bool dA = (w == j), dB = (w == i);
                amax = fmaxf(amax, dA ? 0.0f : va);
                amin = fminf(amin, dA ? 1.0f : va);
                bmax = fmaxf(bmax, dB ? 0.0f : vb);
                bmin = fminf(bmin, dB ? 1.0f : vb);
            }
            rAmax[tid] = amax; rAmin[tid] = amin;
            rBmax[tid] = bmax; rBmin[tid] = bmin;
        }
        __syncthreads();
#pragma unroll
        for (int qq = 0; qq < 2; ++qq) {
            int idx = tid + qq * 256;
            int j2 = idx >> 4, o = idx & 15;
            float acc = bs[o];
#pragma unroll
            for (int cc = 0; cc < 8; ++cc) {
                int jc = j2 * 8 + cc;
                acc += sx1[i * 8 + cc] * Ws[(0 + cc) * 16 + o];
                acc += sx2ij[jc] * Ws[(8 + cc) * 16 + o];
                acc += rAmax[jc] * Ws[(16 + cc) * 16 + o];
                acc += rAmin[jc] * Ws[(24 + cc) * 16 + o];
                acc += sx1[jc] * Ws[(32 + cc) * 16 + o];
                acc += sx2ji[jc] * Ws[(40 + cc) * 16 + o];
                acc += rBmax[jc] * Ws[(48 + cc) * 16 + o];
                acc += rBmin[jc] * Ws[(56 + cc) * 16 + o];
            }
            out2[((size_t)bi * 32 + j2) * 16 + o] = sigmoidf_(acc);
        }
    } else {
        // ================= out0 + out1 =================
        float* s2max = sm;        // 256
        float* s2min = sm + 256;  // 256
        float* sx1 = sm + 512;    // 256
        float* sx0 = sm + 768;    // 8
        float* m1max = sm + 776;  // 8
        float* m1min = sm + 784;  // 8
        int b = blk - 1536;
        int i = tid >> 3, c = tid & 7;
        {
            const float* p = x2 + ((size_t)(b * 32 + i) * 32) * 8 + c;
            float vmax = -1e30f, vmin = 1e30f;
            for (int j2 = 0; j2 < 32; ++j2) {
                float v = p[j2 * 8];
                vmax = fmaxf(vmax, (j2 == i) ? 0.0f : v);
                vmin = fminf(vmin, (j2 == i) ? 1.0f : v);
            }
            s2max[tid] = vmax;
            s2min[tid] = vmin;
        }
        sx1[tid] = x1[(size_t)b * 256 + tid];
        if (tid < 8) sx0[tid] = x0[b * 8 + tid];
        __syncthreads();
        if (tid < 8) {
            float mx = -1e30f, mn = 1e30f;
            for (int ii = 0; ii < 32; ++ii) {
                float v = sx1[ii * 8 + tid];
                mx = fmaxf(mx, v);
                mn = fminf(mn, v);
            }
            m1max[tid] = mx;
            m1min[tid] = mn;
        }
        __syncthreads();
#pragma unroll
        for (int qq = 0; qq < 2; ++qq) {
            int idx = tid + qq * 256;
            int i2 = idx >> 4, o = idx & 15;
            float acc = b1[o];
#pragma unroll
            for (int cc = 0; cc < 8; ++cc) {
                acc += sx0[cc] * W1[cc * 16 + o];
                acc += sx1[i2 * 8 + cc] * W1[(8 + cc) * 16 + o];
                acc += s2max[i2 * 8 + cc] * W1[(16 + cc) * 16 + o];
                acc += s2min[i2 * 8 + cc] * W1[(24 + cc) * 16 + o];
            }
            out1[((size_t)b * 32 + i2) * 16 + o] = sigmoidf_(acc);
        }
        if (tid < 16) {
            int o = tid;
            float acc = b0[o];
#pragma unroll
            for (int cc = 0; cc < 8; ++cc) {
                acc += sx0[cc] * W0[cc * 16 + o];
                acc += m1max[cc] * W0[(8 + cc) * 16 + o];
                acc += m1min[cc] * W0[(16 + cc) * 16 + o];
            }
            out0[b * 16 + o] = sigmoidf_(acc);
        }
    }
}

extern "C" void kernel_launch(void* const* d_in, const int* in_sizes, int n_in, void* d_out,
                              int out_size, void* d_ws, size_t ws_size, hipStream_t stream) {
    // Identify inputs by their UNIQUE flat element counts (robust to ordering).
    const float *x0 = nullptr, *x1 = nullptr, *x2 = nullptr, *x3 = nullptr;
    const float *W0 = nullptr, *W1 = nullptr, *W2 = nullptr, *W3 = nullptr;
    const float* bb[4] = {nullptr, nullptr, nullptr, nullptr};
    int nb = 0;
    for (int k = 0; k < n_in; ++k) {
        const float* p = (const float*)d_in[k];
        switch (in_sizes[k]) {
            case 128:     x0 = p; break;
            case 4096:    x1 = p; break;
            case 131072:  x2 = p; break;
            case 4194304: x3 = p; break;
            case 384:     W0 = p; break;
            case 512:     W1 = p; break;
            case 1024:    W2 = p; break;
            case 1536:    W3 = p; break;
            case 16:      if (nb < 4) bb[nb++] = p; break;
            default: break;
        }
    }
    if (!x0) x0 = (const float*)d_in[0];
    if (!x1) x1 = (const float*)d_in[1];
    if (!x2) x2 = (const float*)d_in[2];
    if (!x3) x3 = (const float*)d_in[3];
    if (!W0) W0 = (const float*)d_in[4];
    if (!W1) W1 = (const float*)d_in[6];
    if (!W2) W2 = (const float*)d_in[8];
    if (!W3) W3 = (const float*)d_in[10];
    const float* b0 = nb > 0 ? bb[0] : (const float*)d_in[5];
    const float* b1 = nb > 1 ? bb[1] : (const float*)d_in[7];
    const float* b2 = nb > 2 ? bb[2] : (const float*)d_in[9];
    const float* b3 = nb > 3 ? bb[3] : (const float*)d_in[11];

    // Output is FP32 (reference output dtype), concatenated flat in return order.
    float* out = (float*)d_out;
    float* out0 = out;           // [16,16]          = 256
    float* out1 = out + 256;     // [16,32,16]       = 8192
    float* out2 = out + 8448;    // [16,32,32,16]    = 262144
    float* out3 = out + 270592;  // [16,32,32,32,16] = 8388608

    k_fused<<<1552, 256, 0, stream>>>(x0, x1, x2, x3, W0, b0, W1, b1, W2, b2, W3, b3,
                                      out0, out1, out2, out3);
}